// Round 4
// baseline (225.598 us; speedup 1.0000x reference)
//
#include <hip/hip_runtime.h>

#define DIM 512
#define NTOK 2304
#define HEADS 8
#define HD 64
#define LN_EPS 1e-5f
#define BNC 2359296   // B*N*C = 2*2304*512
#define QSC 0.18033688011112042f   // 0.125 * log2(e): softmax in exp2 domain

typedef __attribute__((ext_vector_type(8))) short short8;
typedef __attribute__((ext_vector_type(4))) short sh4;
typedef __attribute__((ext_vector_type(4))) float f32x4;

__device__ __forceinline__ short f2bf(float f) {
    union { float f; unsigned u; } x; x.f = f;
    unsigned r = (x.u + 0x7fffu + ((x.u >> 16) & 1u)) >> 16;
    return (short)(r & 0xffffu);
}
__device__ __forceinline__ unsigned fbits(float f) {
    union { float f; unsigned u; } x; x.f = f; return x.u;
}
// async global->LDS DMA, 16B/lane; lds dest = wave-uniform base + lane*16
__device__ __forceinline__ void gl2lds(const short* g, short* l) {
    __builtin_amdgcn_global_load_lds(
        (const __attribute__((address_space(1))) unsigned int*)g,
        (__attribute__((address_space(3))) unsigned int*)l, 16, 0, 0);
}

// -------- fused pre: stats+normalize+transpose (blocks 0..1151) + weight transpose (1152..1343) --------
__global__ void k_pre(const float* __restrict__ x, const float* __restrict__ y,
                      const float* __restrict__ qv_w, const float* __restrict__ k_w,
                      const float* __restrict__ qv_b, const float* __restrict__ k_b,
                      const float* __restrict__ gx, const float* __restrict__ bx,
                      const float* __restrict__ gy, const float* __restrict__ by,
                      short* __restrict__ T, short* __restrict__ Wt,
                      float* __restrict__ bias) {
    __shared__ __align__(16) float tile[64][65];
    __shared__ float pS[4][64], pQ[4][64];
    __shared__ float muL[64], rsL[64];
    int bkid = blockIdx.x, tid = threadIdx.x;
    if (bkid < 1152) {
        int nt = bkid % 36, ct = (bkid / 36) % 8, sb = bkid / 288;
        int s = sb >> 1, b = sb & 1;
        int n0 = nt * 64, c0 = ct * 64;
        const float* src = (s ? y : x) + (size_t)b * DIM * NTOK;
        // phase 1: LN stats for tokens n0..n0+63 (full 512-c read, 4-way split)
        int nl = tid & 63, part = tid >> 6;
        {
            const float* p = src + n0 + nl;
            float sum = 0.f, sq = 0.f;
            for (int c = part * 128; c < part * 128 + 128; c++) {
                float v = p[(size_t)c * NTOK];
                sum += v; sq += v * v;
            }
            pS[part][nl] = sum; pQ[part][nl] = sq;
        }
        __syncthreads();
        if (tid < 64) {
            float ts = pS[0][tid] + pS[1][tid] + pS[2][tid] + pS[3][tid];
            float tq = pQ[0][tid] + pQ[1][tid] + pQ[2][tid] + pQ[3][tid];
            float m = ts * (1.0f / DIM);
            float var = tq * (1.0f / DIM) - m * m;
            muL[tid] = m;
            rsL[tid] = rsqrtf(var + LN_EPS);
        }
        // phase 2: load c-tile, normalize, transpose-store
        for (int slot = tid; slot < 1024; slot += 256) {
            int r = slot >> 4, q = slot & 15;
            const float* p = src + (size_t)(c0 + r) * NTOK + n0 + q * 4;
            float4 v = *(const float4*)p;
            tile[r][q*4+0] = v.x; tile[r][q*4+1] = v.y;
            tile[r][q*4+2] = v.z; tile[r][q*4+3] = v.w;
        }
        __syncthreads();   // covers muL/rsL and tile
        const float* g  = s ? gy : gx;
        const float* be = s ? by : bx;
        int nr = tid >> 2, cg = tid & 3;
        float m = muL[nr], r_ = rsL[nr];
        short8 o0, o1;
        for (int i = 0; i < 8; i++) {
            int c = c0 + cg * 16 + i;
            o0[i] = f2bf((tile[cg*16+i][nr] - m) * r_ * g[c] + be[c]);
        }
        for (int i = 0; i < 8; i++) {
            int c = c0 + cg * 16 + 8 + i;
            o1[i] = f2bf((tile[cg*16+8+i][nr] - m) * r_ * g[c] + be[c]);
        }
        short* dst = T + ((size_t)sb * NTOK + n0 + nr) * DIM + c0 + cg * 16;
        *(short8*)dst = o0;
        *(short8*)(dst + 8) = o1;
        return;
    }
    // ---- weight transpose blocks ----
    int idx = bkid - 1152;
    int jt = idx % 24, ct = idx / 24;
    int j0 = jt * 64, c0 = ct * 64;
    if (ct == 0 && tid < 64) {
        int j = j0 + tid;
        bias[j] = (j < 1024) ? qv_b[j] : k_b[j - 1024];
    }
    for (int slot = tid; slot < 1024; slot += 256) {
        int r = slot >> 4, q = slot & 15;
        int c = c0 + r;
        float4 v;
        if (j0 < 1024) v = *(const float4*)(qv_w + (size_t)c * 1024 + j0 + q * 4);
        else           v = *(const float4*)(k_w  + (size_t)c * 512  + (j0 - 1024) + q * 4);
        tile[r][q*4+0] = v.x; tile[r][q*4+1] = v.y;
        tile[r][q*4+2] = v.z; tile[r][q*4+3] = v.w;
    }
    __syncthreads();
    int jr = tid >> 2, cg = tid & 3;
    short8 o0, o1;
    for (int i = 0; i < 8; i++) o0[i] = f2bf(tile[cg*16+i][jr]);
    for (int i = 0; i < 8; i++) o1[i] = f2bf(tile[cg*16+8+i][jr]);
    short* dst = Wt + (size_t)(j0 + jr) * DIM + c0 + cg * 16;
    *(short8*)dst = o0;
    *(short8*)(dst + 8) = o1;
}

// -------- GEMM: 128x128 tile, DMA staging + XOR swizzle, Q pre-scaled --------
__global__ void __launch_bounds__(256)
k_gemm(const short* __restrict__ T, const short* __restrict__ Wt,
       const float* __restrict__ bias, short* __restrict__ QVK,
       short* __restrict__ VT) {
    __shared__ __align__(16) short smem[2 * 128 * 64];
    short* As = smem;
    short* Bs = smem + 128 * 64;
    int n0 = blockIdx.x * 128, j0 = blockIdx.y * 128, sb = blockIdx.z;
    int tid = threadIdx.x;
    int w = tid >> 6, l = tid & 63;
    int wr = w >> 1, wc = w & 1;
    int lrow = l & 15, quad = l >> 4;
    int r_in = (l >> 3) & 7, cc = l & 7;
    int ch = cc ^ r_in;                       // swizzled source chunk
    int sw0 = (quad ^ (lrow & 7)) * 8;        // frag-read chunk offset (shorts)
    const short* Ab = T + (size_t)sb * NTOK * DIM;
    f32x4 acc[4][4] = {};
    for (int kk = 0; kk < 8; kk++) {
        if (kk) __syncthreads();
        for (int inst = 0; inst < 4; inst++) {
            int R = w * 32 + inst * 8 + r_in;
            gl2lds(Ab + (size_t)(n0 + R) * 512 + kk * 64 + ch * 8,
                   &As[(w * 32 + inst * 8) * 64]);
            gl2lds(Wt + (size_t)(j0 + R) * 512 + kk * 64 + ch * 8,
                   &Bs[(w * 32 + inst * 8) * 64]);
        }
        __syncthreads();
        for (int c2 = 0; c2 < 2; c2++) {
            int off = c2 ? (sw0 ^ 32) : sw0;
            short8 af[4], bf[4];
            for (int i = 0; i < 4; i++)
                af[i] = *(const short8*)&As[(wr*64 + i*16 + lrow) * 64 + off];
            for (int j = 0; j < 4; j++)
                bf[j] = *(const short8*)&Bs[(wc*64 + j*16 + lrow) * 64 + off];
            for (int i = 0; i < 4; i++)
                for (int j = 0; j < 4; j++)
                    acc[i][j] = __builtin_amdgcn_mfma_f32_16x16x32_bf16(af[i], bf[j], acc[i][j], 0, 0, 0);
        }
    }
    if (j0 >= 512 && j0 < 1024) {
        // ---- V block: transpose tile in LDS (reuse As+Bs as 128x128), write VT ----
        __syncthreads();               // main-loop LDS readers done
        for (int i = 0; i < 4; i++)
            for (int j = 0; j < 4; j++) {
                int jloc = wc * 64 + j * 16 + lrow;           // V row (within tile)
                float bv = bias[j0 + jloc];
                int nloc = wr * 64 + i * 16 + quad * 4;       // n col
                int c8 = nloc >> 3, half = (nloc >> 2) & 1;
                sh4 pk;
                for (int reg = 0; reg < 4; reg++) pk[reg] = f2bf(acc[i][j][reg] + bv);
                *(sh4*)&smem[jloc * 128 + ((c8 ^ (jloc & 15)) * 8) + half * 4] = pk;
            }
        __syncthreads();
        for (int slot = tid; slot < 2048; slot += 256) {
            int row = slot >> 4, seg = slot & 15;
            short8 v = *(const short8*)&smem[row * 128 + ((seg ^ (row & 15)) * 8)];
            *(short8*)(VT + ((size_t)sb * 512 + (j0 - 512) + row) * NTOK + n0 + seg * 8) = v;
        }
    } else {
        for (int i = 0; i < 4; i++)
            for (int j = 0; j < 4; j++) {
                int jj = j0 + wc * 64 + j * 16 + lrow;
                float bv = bias[jj];
                float sc = (jj < 512) ? QSC : 1.0f;   // Q pre-scaled into exp2 domain
                for (int reg = 0; reg < 4; reg++) {
                    int n = n0 + wr * 64 + i * 16 + quad * 4 + reg;
                    QVK[((size_t)sb * NTOK + n) * 1536 + jj] = f2bf((acc[i][j][reg] + bv) * sc);
                }
            }
    }
}

// ---------------- flash attention: 2 waves x 32 Q-rows (LDS read-amp halved) ----------------
// R13 theory: LDS-read accounting shows ~4 GB of ds_read traffic (each of 4
// waves re-reads the full K and V tiles as A-fragments -> 4x amplification)
// ~= 52% of runtime at 128 B/clk/CU. K/V reads per wave are invariant to MFMA
// shape and tile size; they scale only with 1/(Q-rows per wave). So: 2 waves x
// 32 Q-rows (block still 64 rows, grid unchanged 1152, same XCD swizzle). Per
// block-tile LDS reads 72->40 KB; each wave gets 2 independent acc chains (qb).
// R15: R13/R14 failed because the host launch stayed at 256 threads while the
// kernel is __launch_bounds__(128) -> dispatch never ran, out stayed zeroed
// (absmax 0.0927 == max|ref|). Device code unchanged; launch fixed to 128.
__global__ void __launch_bounds__(128)
k_attn(const short* __restrict__ QVK, const short* __restrict__ VT,
       float* __restrict__ out) {
    __shared__ __align__(16) short Ks[64 * 64];
    __shared__ __align__(16) short Vs[64 * 64];
    __shared__ __align__(16) short Qs[64 * 64];   // Q staging; re-used as P (wave-private)
    int id = blockIdx.x;              // 0..1151
    int xcd = id & 7, rem = id >> 3;
    int qt = rem % 36, yhi = rem / 36;
    int yb = yhi * 8 + xcd;           // 0..31
    int br = yb >> 4;
    int b  = (yb >> 3) & 1;
    int h  = yb & 7;
    int tid = threadIdx.x;
    int w = tid >> 6, l = tid & 63;   // w in {0,1}
    int lrow = l & 15, quad = l >> 4;
    int r_in = (l >> 3) & 7, cc = l & 7;
    int ch = cc ^ r_in;
    int sw0 = (quad ^ (lrow & 7)) * 8;
    int n0 = qt * 64;
    const short* Qg = QVK + ((size_t)(br * 2 + b) * NTOK) * 1536 + h * 64;           // exp2-scaled Q
    const short* Kg = QVK + ((size_t)((1 - br) * 2 + b) * NTOK) * 1536 + 1024 + h * 64;
    const short* Vg = VT + ((size_t)(br * 2 + b) * 512 + h * 64) * NTOK;

    // stage Q (wave w: rows w*32..w*32+31)
    #pragma unroll
    for (int j = 0; j < 4; j++) {
        int R = w * 32 + j * 8 + r_in;
        gl2lds(Qg + (size_t)(n0 + R) * 1536 + ch * 8, &Qs[(w * 32 + j * 8) * 64]);
    }

    // per-lane global source addresses for K/V staging (4 groups of 8 rows)
    const short* Kp = Kg + (size_t)(w * 32 + r_in) * 1536 + ch * 8;   // +(m0+j*8)*1536
    const short* Vp = Vg + (size_t)(w * 32 + r_in) * NTOK + ch * 8;   // +j*8*NTOK + m0
    int lds_base = (w * 32) * 64 + l * 8;     // lane slot (matches 8-row linear groups)

    // prefetch tile 0 into regs (flies under the Q drain + bq reads)
    short8 kr[4], vr[4];
    #pragma unroll
    for (int j = 0; j < 4; j++) {
        kr[j] = *(const short8*)(Kp + (size_t)(j * 8) * 1536);
        vr[j] = *(const short8*)(Vp + (size_t)(j * 8) * NTOK);
    }
    const short* Kc = Kp + (size_t)64 * 1536;   // next-tile bases
    const short* Vc = Vp + 64;

    __syncthreads();                  // Q staged
    short8 bq[2][2];
    #pragma unroll
    for (int qb = 0; qb < 2; qb++) {
        bq[qb][0] = *(const short8*)&Qs[(w * 32 + qb * 16 + lrow) * 64 + sw0];
        bq[qb][1] = *(const short8*)&Qs[(w * 32 + qb * 16 + lrow) * 64 + (sw0 ^ 32)];
    }
    short* Pw = &Qs[(w * 32) * 64];   // wave-private P region (32 rows = own Q rows)

    short8 ones;
    #pragma unroll
    for (int i = 0; i < 8; i++) ones[i] = (short)0x3F80;   // bf16 1.0

    f32x4 Oacc[2][4] = {};
    f32x4 lacc[2] = {};

    for (int mt = 0; mt < 36; mt++) {
        __syncthreads();              // B1: prev-tile LDS readers done; drains prefetch loads
        #pragma unroll
        for (int j = 0; j < 4; j++) {
            *(short8*)&Ks[lds_base + j * 8 * 64] = kr[j];
            *(short8*)&Vs[lds_base + j * 8 * 64] = vr[j];
        }
        __syncthreads();              // B2: all waves' ds_writes visible
        if (mt + 1 < 36) {            // issue tile mt+1 loads; they fly under this tile's compute
            #pragma unroll
            for (int j = 0; j < 4; j++) {
                kr[j] = *(const short8*)(Kc + (size_t)(j * 8) * 1536);
                vr[j] = *(const short8*)(Vc + (size_t)(j * 8) * NTOK);
            }
        }
        Kc += (size_t)64 * 1536;
        Vc += 64;
        __builtin_amdgcn_sched_barrier(0);   // pin prefetch issue above the compute

        #pragma unroll
        for (int sub = 0; sub < 4; sub++) {
            short8 ak0 = *(const short8*)&Ks[(sub * 16 + lrow) * 64 + sw0];
            short8 ak1 = *(const short8*)&Ks[(sub * 16 + lrow) * 64 + (sw0 ^ 32)];
            #pragma unroll
            for (int qb = 0; qb < 2; qb++) {
                f32x4 a = {};
                a = __builtin_amdgcn_mfma_f32_16x16x32_bf16(ak0, bq[qb][0], a, 0, 0, 0);
                a = __builtin_amdgcn_mfma_f32_16x16x32_bf16(ak1, bq[qb][1], a, 0, 0, 0);
                float p0 = exp2f(a[0]), p1 = exp2f(a[1]);
                float p2 = exp2f(a[2]), p3 = exp2f(a[3]);
                uint2 pk;
                pk.x = __builtin_amdgcn_perm(fbits(p1), fbits(p0), 0x07060302u);
                pk.y = __builtin_amdgcn_perm(fbits(p3), fbits(p2), 0x07060302u);
                *(uint2*)&Pw[(qb * 16 + lrow) * 64 +
                             (((2 * sub + (quad >> 1)) ^ (lrow & 7)) * 8) + (quad & 1) * 4] = pk;
            }
        }

        // PV + l-sum: same-wave LDS dep only, no barrier
        short8 ap[2][2];
        #pragma unroll
        for (int qb = 0; qb < 2; qb++) {
            ap[qb][0] = *(const short8*)&Pw[(qb * 16 + lrow) * 64 + sw0];
            ap[qb][1] = *(const short8*)&Pw[(qb * 16 + lrow) * 64 + (sw0 ^ 32)];
            lacc[qb] = __builtin_amdgcn_mfma_f32_16x16x32_bf16(ones, ap[qb][0], lacc[qb], 0, 0, 0);
            lacc[qb] = __builtin_amdgcn_mfma_f32_16x16x32_bf16(ones, ap[qb][1], lacc[qb], 0, 0, 0);
        }
        #pragma unroll
        for (int ddt = 0; ddt < 4; ddt++) {
            short8 av0 = *(const short8*)&Vs[(ddt * 16 + lrow) * 64 + sw0];
            short8 av1 = *(const short8*)&Vs[(ddt * 16 + lrow) * 64 + (sw0 ^ 32)];
            #pragma unroll
            for (int qb = 0; qb < 2; qb++) {
                Oacc[qb][ddt] = __builtin_amdgcn_mfma_f32_16x16x32_bf16(av0, ap[qb][0], Oacc[qb][ddt], 0, 0, 0);
                Oacc[qb][ddt] = __builtin_amdgcn_mfma_f32_16x16x32_bf16(av1, ap[qb][1], Oacc[qb][ddt], 0, 0, 0);
            }
        }
    }

    #pragma unroll
    for (int qb = 0; qb < 2; qb++) {
        float linv = 1.f / lacc[qb][0];   // all rows of lacc identical (ones A-operand)
        int n = n0 + w * 32 + qb * 16 + lrow;
        #pragma unroll
        for (int ddt = 0; ddt < 4; ddt++) {
            float4 o;
            o.x = Oacc[qb][ddt][0] * linv;
            o.y = Oacc[qb][ddt][1] * linv;
            o.z = Oacc[qb][ddt][2] * linv;
            o.w = Oacc[qb][ddt][3] * linv;
            if (br == 0)
                *(float4*)&out[((size_t)b * NTOK + n) * 512 + h * 64 + ddt * 16 + quad * 4] = o;
            else
                *(float4*)&out[(size_t)BNC + ((size_t)(h * 2 + b) * NTOK + n) * 64 + ddt * 16 + quad * 4] = o;
        }
    }
}

extern "C" void kernel_launch(void* const* d_in, const int* in_sizes, int n_in,
                              void* d_out, int out_size, void* d_ws, size_t ws_size,
                              hipStream_t stream) {
    const float* x     = (const float*)d_in[0];
    const float* y     = (const float*)d_in[1];
    const float* k_w   = (const float*)d_in[2];
    const float* k_b   = (const float*)d_in[3];
    const float* qv_w  = (const float*)d_in[4];
    const float* qv_b  = (const float*)d_in[5];
    const float* lnx_g = (const float*)d_in[6];
    const float* lnx_b = (const float*)d_in[7];
    const float* lny_g = (const float*)d_in[8];
    const float* lny_b = (const float*)d_in[9];
    float* out = (float*)d_out;

    char* ws = (char*)d_ws;
    float* bias = (float*)ws;                 // 1536 f32 (6144 B, 16B-aligned)
    short* T    = (short*)(ws + 6144);        // 4,718,592 bf16
    short* Wt   = T + 4718592;                // 786,432 bf16
    short* QVK  = Wt + 786432;                // 14,155,776 bf16 (V region unused)
    short* VT   = QVK + 14155776;             // 4,718,592 bf16

    k_pre  <<<1344, 256, 0, stream>>>(x, y, qv_w, k_w, qv_b, k_b,
                                      lnx_g, lnx_b, lny_g, lny_b, T, Wt, bias);
    k_gemm <<<dim3(18, 12, 4), 256, 0, stream>>>(T, Wt, bias, QVK, VT);
    k_attn <<<1152, 128, 0, stream>>>(QVK, VT, out);   // 128 = 2 waves (matches __launch_bounds__)
}

// Round 5
// 202.278 us; speedup vs baseline: 1.1153x; 1.1153x over previous
//
#include <hip/hip_runtime.h>

#define DIM 512
#define NTOK 2304
#define HEADS 8
#define HD 64
#define LN_EPS 1e-5f
#define BNC 2359296   // B*N*C = 2*2304*512
#define QSC 0.18033688011112042f   // 0.125 * log2(e): softmax in exp2 domain

typedef __attribute__((ext_vector_type(8))) short short8;
typedef __attribute__((ext_vector_type(4))) short sh4;
typedef __attribute__((ext_vector_type(4))) float f32x4;

__device__ __forceinline__ short f2bf(float f) {
    union { float f; unsigned u; } x; x.f = f;
    unsigned r = (x.u + 0x7fffu + ((x.u >> 16) & 1u)) >> 16;
    return (short)(r & 0xffffu);
}
__device__ __forceinline__ unsigned fbits(float f) {
    union { float f; unsigned u; } x; x.f = f; return x.u;
}
// async global->LDS DMA, 16B/lane; lds dest = wave-uniform base + lane*16
__device__ __forceinline__ void gl2lds(const short* g, short* l) {
    __builtin_amdgcn_global_load_lds(
        (const __attribute__((address_space(1))) unsigned int*)g,
        (__attribute__((address_space(3))) unsigned int*)l, 16, 0, 0);
}

// -------- fused pre: stats+normalize+transpose (blocks 0..1151) + weight transpose (1152..1343) --------
__global__ void k_pre(const float* __restrict__ x, const float* __restrict__ y,
                      const float* __restrict__ qv_w, const float* __restrict__ k_w,
                      const float* __restrict__ qv_b, const float* __restrict__ k_b,
                      const float* __restrict__ gx, const float* __restrict__ bx,
                      const float* __restrict__ gy, const float* __restrict__ by,
                      short* __restrict__ T, short* __restrict__ Wt,
                      float* __restrict__ bias) {
    __shared__ __align__(16) float tile[64][65];
    __shared__ float pS[4][64], pQ[4][64];
    __shared__ float muL[64], rsL[64];
    int bkid = blockIdx.x, tid = threadIdx.x;
    if (bkid < 1152) {
        int nt = bkid % 36, ct = (bkid / 36) % 8, sb = bkid / 288;
        int s = sb >> 1, b = sb & 1;
        int n0 = nt * 64, c0 = ct * 64;
        const float* src = (s ? y : x) + (size_t)b * DIM * NTOK;
        // phase 1: LN stats for tokens n0..n0+63 (full 512-c read, 4-way split)
        int nl = tid & 63, part = tid >> 6;
        {
            const float* p = src + n0 + nl;
            float sum = 0.f, sq = 0.f;
            for (int c = part * 128; c < part * 128 + 128; c++) {
                float v = p[(size_t)c * NTOK];
                sum += v; sq += v * v;
            }
            pS[part][nl] = sum; pQ[part][nl] = sq;
        }
        __syncthreads();
        if (tid < 64) {
            float ts = pS[0][tid] + pS[1][tid] + pS[2][tid] + pS[3][tid];
            float tq = pQ[0][tid] + pQ[1][tid] + pQ[2][tid] + pQ[3][tid];
            float m = ts * (1.0f / DIM);
            float var = tq * (1.0f / DIM) - m * m;
            muL[tid] = m;
            rsL[tid] = rsqrtf(var + LN_EPS);
        }
        // phase 2: load c-tile, normalize, transpose-store
        for (int slot = tid; slot < 1024; slot += 256) {
            int r = slot >> 4, q = slot & 15;
            const float* p = src + (size_t)(c0 + r) * NTOK + n0 + q * 4;
            float4 v = *(const float4*)p;
            tile[r][q*4+0] = v.x; tile[r][q*4+1] = v.y;
            tile[r][q*4+2] = v.z; tile[r][q*4+3] = v.w;
        }
        __syncthreads();   // covers muL/rsL and tile
        const float* g  = s ? gy : gx;
        const float* be = s ? by : bx;
        int nr = tid >> 2, cg = tid & 3;
        float m = muL[nr], r_ = rsL[nr];
        short8 o0, o1;
        for (int i = 0; i < 8; i++) {
            int c = c0 + cg * 16 + i;
            o0[i] = f2bf((tile[cg*16+i][nr] - m) * r_ * g[c] + be[c]);
        }
        for (int i = 0; i < 8; i++) {
            int c = c0 + cg * 16 + 8 + i;
            o1[i] = f2bf((tile[cg*16+8+i][nr] - m) * r_ * g[c] + be[c]);
        }
        short* dst = T + ((size_t)sb * NTOK + n0 + nr) * DIM + c0 + cg * 16;
        *(short8*)dst = o0;
        *(short8*)(dst + 8) = o1;
        return;
    }
    // ---- weight transpose blocks ----
    int idx = bkid - 1152;
    int jt = idx % 24, ct = idx / 24;
    int j0 = jt * 64, c0 = ct * 64;
    if (ct == 0 && tid < 64) {
        int j = j0 + tid;
        bias[j] = (j < 1024) ? qv_b[j] : k_b[j - 1024];
    }
    for (int slot = tid; slot < 1024; slot += 256) {
        int r = slot >> 4, q = slot & 15;
        int c = c0 + r;
        float4 v;
        if (j0 < 1024) v = *(const float4*)(qv_w + (size_t)c * 1024 + j0 + q * 4);
        else           v = *(const float4*)(k_w  + (size_t)c * 512  + (j0 - 1024) + q * 4);
        tile[r][q*4+0] = v.x; tile[r][q*4+1] = v.y;
        tile[r][q*4+2] = v.z; tile[r][q*4+3] = v.w;
    }
    __syncthreads();
    int jr = tid >> 2, cg = tid & 3;
    short8 o0, o1;
    for (int i = 0; i < 8; i++) o0[i] = f2bf(tile[cg*16+i][jr]);
    for (int i = 0; i < 8; i++) o1[i] = f2bf(tile[cg*16+8+i][jr]);
    short* dst = Wt + (size_t)(j0 + jr) * DIM + c0 + cg * 16;
    *(short8*)dst = o0;
    *(short8*)(dst + 8) = o1;
}

// -------- GEMM: 128x128 tile, DMA staging + XOR swizzle, Q pre-scaled --------
__global__ void __launch_bounds__(256)
k_gemm(const short* __restrict__ T, const short* __restrict__ Wt,
       const float* __restrict__ bias, short* __restrict__ QVK,
       short* __restrict__ VT) {
    __shared__ __align__(16) short smem[2 * 128 * 64];
    short* As = smem;
    short* Bs = smem + 128 * 64;
    int n0 = blockIdx.x * 128, j0 = blockIdx.y * 128, sb = blockIdx.z;
    int tid = threadIdx.x;
    int w = tid >> 6, l = tid & 63;
    int wr = w >> 1, wc = w & 1;
    int lrow = l & 15, quad = l >> 4;
    int r_in = (l >> 3) & 7, cc = l & 7;
    int ch = cc ^ r_in;                       // swizzled source chunk
    int sw0 = (quad ^ (lrow & 7)) * 8;        // frag-read chunk offset (shorts)
    const short* Ab = T + (size_t)sb * NTOK * DIM;
    f32x4 acc[4][4] = {};
    for (int kk = 0; kk < 8; kk++) {
        if (kk) __syncthreads();
        for (int inst = 0; inst < 4; inst++) {
            int R = w * 32 + inst * 8 + r_in;
            gl2lds(Ab + (size_t)(n0 + R) * 512 + kk * 64 + ch * 8,
                   &As[(w * 32 + inst * 8) * 64]);
            gl2lds(Wt + (size_t)(j0 + R) * 512 + kk * 64 + ch * 8,
                   &Bs[(w * 32 + inst * 8) * 64]);
        }
        __syncthreads();
        for (int c2 = 0; c2 < 2; c2++) {
            int off = c2 ? (sw0 ^ 32) : sw0;
            short8 af[4], bf[4];
            for (int i = 0; i < 4; i++)
                af[i] = *(const short8*)&As[(wr*64 + i*16 + lrow) * 64 + off];
            for (int j = 0; j < 4; j++)
                bf[j] = *(const short8*)&Bs[(wc*64 + j*16 + lrow) * 64 + off];
            for (int i = 0; i < 4; i++)
                for (int j = 0; j < 4; j++)
                    acc[i][j] = __builtin_amdgcn_mfma_f32_16x16x32_bf16(af[i], bf[j], acc[i][j], 0, 0, 0);
        }
    }
    if (j0 >= 512 && j0 < 1024) {
        // ---- V block: transpose tile in LDS (reuse As+Bs as 128x128), write VT ----
        __syncthreads();               // main-loop LDS readers done
        for (int i = 0; i < 4; i++)
            for (int j = 0; j < 4; j++) {
                int jloc = wc * 64 + j * 16 + lrow;           // V row (within tile)
                float bv = bias[j0 + jloc];
                int nloc = wr * 64 + i * 16 + quad * 4;       // n col
                int c8 = nloc >> 3, half = (nloc >> 2) & 1;
                sh4 pk;
                for (int reg = 0; reg < 4; reg++) pk[reg] = f2bf(acc[i][j][reg] + bv);
                *(sh4*)&smem[jloc * 128 + ((c8 ^ (jloc & 15)) * 8) + half * 4] = pk;
            }
        __syncthreads();
        for (int slot = tid; slot < 2048; slot += 256) {
            int row = slot >> 4, seg = slot & 15;
            short8 v = *(const short8*)&smem[row * 128 + ((seg ^ (row & 15)) * 8)];
            *(short8*)(VT + ((size_t)sb * 512 + (j0 - 512) + row) * NTOK + n0 + seg * 8) = v;
        }
    } else {
        for (int i = 0; i < 4; i++)
            for (int j = 0; j < 4; j++) {
                int jj = j0 + wc * 64 + j * 16 + lrow;
                float bv = bias[jj];
                float sc = (jj < 512) ? QSC : 1.0f;   // Q pre-scaled into exp2 domain
                for (int reg = 0; reg < 4; reg++) {
                    int n = n0 + wr * 64 + i * 16 + quad * 4 + reg;
                    QVK[((size_t)sb * NTOK + n) * 1536 + jj] = f2bf((acc[i][j][reg] + bv) * sc);
                }
            }
    }
}

// ---------------- flash attention: R1 4-wave core + KV-split x2 ----------------
// R16: R4 proved k_attn is latency/occupancy-bound (halving waves cost +25%;
// MFMA/VALU totals unchanged). Grid 1152 = 4.5 blocks/CU -> 20% quantization
// tail AND grid-limited 18 waves/CU (LDS allows 24). Softmax here is plain
// sum-exp2 (no running max), so the KV loop splits exactly across 2 blocks:
// half h sums tiles [h*18, h*18+18). Grid 2304 = 9.0/CU even; 6 resident
// blocks/CU (24 waves). Half 0 stores unnormalized O to out; half 1 to O1
// (f32 ws) + per-row l0/l1; k_norm combines: out=(out+O1)/(l0+l1).
__global__ void __launch_bounds__(256)
k_attn(const short* __restrict__ QVK, const short* __restrict__ VT,
       float* __restrict__ out, float* __restrict__ O1,
       float* __restrict__ l0, float* __restrict__ l1) {
    __shared__ __align__(16) short Ks[64 * 64];
    __shared__ __align__(16) short Vs[64 * 64];
    __shared__ __align__(16) short Qs[64 * 64];   // Q staging; re-used as P (wave-private)
    int id = blockIdx.x;              // 0..2303
    int half = id / 1152;             // KV half
    int rid = id % 1152;
    int xcd = rid & 7, rem = rid >> 3;
    int qt = rem % 36, yhi = rem / 36;
    int yb = yhi * 8 + xcd;           // 0..31
    int br = yb >> 4;
    int b  = (yb >> 3) & 1;
    int h  = yb & 7;
    int tid = threadIdx.x;
    int w = tid >> 6, l = tid & 63;
    int lrow = l & 15, quad = l >> 4;
    int r_in = (l >> 3) & 7, cc = l & 7;
    int ch = cc ^ r_in;
    int sw0 = (quad ^ (lrow & 7)) * 8;
    int n0 = qt * 64;
    int m_base = half * 1152;         // 18 tiles x 64 rows
    const short* Qg = QVK + ((size_t)(br * 2 + b) * NTOK) * 1536 + h * 64;           // exp2-scaled Q
    const short* Kg = QVK + ((size_t)((1 - br) * 2 + b) * NTOK) * 1536 + 1024 + h * 64;
    const short* Vg = VT + ((size_t)(br * 2 + b) * 512 + h * 64) * NTOK;

    // stage Q (wave w: rows w*16..w*16+15)
    for (int inst = 0; inst < 2; inst++) {
        int R = w * 16 + inst * 8 + r_in;
        gl2lds(Qg + (size_t)(n0 + R) * 1536 + ch * 8, &Qs[(w * 16 + inst * 8) * 64]);
    }

    // per-thread global source addresses (row pair of this wave's 16-row slab)
    const short* KgA = Kg + (size_t)(m_base + w * 16 + r_in) * 1536 + ch * 8;
    const short* KgB = Kg + (size_t)(m_base + w * 16 + 8 + r_in) * 1536 + ch * 8;
    const short* VgA = Vg + (size_t)(w * 16 + r_in) * NTOK + m_base + ch * 8;
    const short* VgB = Vg + (size_t)(w * 16 + 8 + r_in) * NTOK + m_base + ch * 8;
    int lds_off = l * 8;              // lane slot: matches gl2lds's implicit lane*16B

    // prefetch tile 0 into regs (flies under the Q drain + bq reads)
    short8 ka = *(const short8*)(KgA);
    short8 kb = *(const short8*)(KgB);
    short8 va = *(const short8*)(VgA);
    short8 vb = *(const short8*)(VgB);
    const short* Kc = KgA + (size_t)64 * 1536;   // next-tile bases
    const short* Kd = KgB + (size_t)64 * 1536;
    const short* Vc = VgA + 64;
    const short* Vd = VgB + 64;

    __syncthreads();                  // Q staged
    short8 bq0 = *(const short8*)&Qs[(w * 16 + lrow) * 64 + sw0];
    short8 bq1 = *(const short8*)&Qs[(w * 16 + lrow) * 64 + (sw0 ^ 32)];
    short* Pw = &Qs[w * 16 * 64];     // wave-private P region (16 rows)

    short8 ones;
    for (int i = 0; i < 8; i++) ones[i] = (short)0x3F80;   // bf16 1.0

    f32x4 Oacc[4] = {};
    f32x4 lacc = {};

    for (int mt = 0; mt < 18; mt++) {
        __syncthreads();              // B1: prev-tile LDS readers done; drains prefetch loads
        *(short8*)&Ks[(w * 16)     * 64 + lds_off] = ka;
        *(short8*)&Ks[(w * 16 + 8) * 64 + lds_off] = kb;
        *(short8*)&Vs[(w * 16)     * 64 + lds_off] = va;
        *(short8*)&Vs[(w * 16 + 8) * 64 + lds_off] = vb;
        __syncthreads();              // B2: all waves' ds_writes visible
        if (mt + 1 < 18) {            // issue tile mt+1 loads; they fly under this tile's compute
            ka = *(const short8*)(Kc);
            kb = *(const short8*)(Kd);
            va = *(const short8*)(Vc);
            vb = *(const short8*)(Vd);
        }
        Kc += (size_t)64 * 1536;
        Kd += (size_t)64 * 1536;
        Vc += 64;
        Vd += 64;
        __builtin_amdgcn_sched_barrier(0);   // pin prefetch issue above the compute

        for (int sub = 0; sub < 4; sub++) {
            short8 ak0 = *(const short8*)&Ks[(sub * 16 + lrow) * 64 + sw0];
            short8 ak1 = *(const short8*)&Ks[(sub * 16 + lrow) * 64 + (sw0 ^ 32)];
            f32x4 a = {};
            a = __builtin_amdgcn_mfma_f32_16x16x32_bf16(ak0, bq0, a, 0, 0, 0);
            a = __builtin_amdgcn_mfma_f32_16x16x32_bf16(ak1, bq1, a, 0, 0, 0);
            float p0 = exp2f(a[0]), p1 = exp2f(a[1]);
            float p2 = exp2f(a[2]), p3 = exp2f(a[3]);
            uint2 pk;
            pk.x = __builtin_amdgcn_perm(fbits(p1), fbits(p0), 0x07060302u);
            pk.y = __builtin_amdgcn_perm(fbits(p3), fbits(p2), 0x07060302u);
            *(uint2*)&Pw[lrow * 64 + (((2 * sub + (quad >> 1)) ^ (lrow & 7)) * 8) + (quad & 1) * 4] = pk;
        }

        // PV + l-sum: same-wave LDS dep only, no barrier
        short8 ap0 = *(const short8*)&Pw[lrow * 64 + sw0];
        short8 ap1 = *(const short8*)&Pw[lrow * 64 + (sw0 ^ 32)];
        lacc = __builtin_amdgcn_mfma_f32_16x16x32_bf16(ones, ap0, lacc, 0, 0, 0);
        lacc = __builtin_amdgcn_mfma_f32_16x16x32_bf16(ones, ap1, lacc, 0, 0, 0);
        for (int ddt = 0; ddt < 4; ddt++) {
            short8 av0 = *(const short8*)&Vs[(ddt * 16 + lrow) * 64 + sw0];
            short8 av1 = *(const short8*)&Vs[(ddt * 16 + lrow) * 64 + (sw0 ^ 32)];
            Oacc[ddt] = __builtin_amdgcn_mfma_f32_16x16x32_bf16(av0, ap0, Oacc[ddt], 0, 0, 0);
            Oacc[ddt] = __builtin_amdgcn_mfma_f32_16x16x32_bf16(av1, ap1, Oacc[ddt], 0, 0, 0);
        }
    }

    // epilogue: unnormalized partial O + partial l (combined by k_norm)
    int n = n0 + w * 16 + lrow;
    if (quad == 0) (half ? l1 : l0)[yb * NTOK + n] = lacc[0];
    for (int ddt = 0; ddt < 4; ddt++) {
        float4 o;
        o.x = Oacc[ddt][0];
        o.y = Oacc[ddt][1];
        o.z = Oacc[ddt][2];
        o.w = Oacc[ddt][3];
        if (half == 0) {
            if (br == 0)
                *(float4*)&out[((size_t)b * NTOK + n) * 512 + h * 64 + ddt * 16 + quad * 4] = o;
            else
                *(float4*)&out[(size_t)BNC + ((size_t)(h * 2 + b) * NTOK + n) * 64 + ddt * 16 + quad * 4] = o;
        } else {
            *(float4*)&O1[((size_t)yb * NTOK + n) * 64 + ddt * 16 + quad * 4] = o;
        }
    }
}

// ---------------- combine + normalize: out = (out + O1) / (l0 + l1) ----------------
__global__ void __launch_bounds__(256)
k_norm(float* __restrict__ out, const float* __restrict__ O1,
       const float* __restrict__ l0, const float* __restrict__ l1) {
    int i = blockIdx.x * 256 + threadIdx.x;   // float4 index, 1,179,648 total
    int o = i * 4;
    int yb, n, d;
    if (o < BNC) {
        int b = o / (NTOK * 512);
        int r = o % (NTOK * 512);
        n = r >> 9;
        int c = r & 511;
        d = c & 63;
        yb = b * 8 + (c >> 6);
    } else {
        int o2 = o - BNC;
        int hb = o2 / (NTOK * 64);
        n = (o2 >> 6) % NTOK;
        d = o2 & 63;
        yb = 16 + (hb & 1) * 8 + (hb >> 1);
    }
    int li = yb * NTOK + n;
    float linv = 1.f / (l0[li] + l1[li]);
    float4 a = *(const float4*)&out[o];
    float4 q = *(const float4*)&O1[(size_t)li * 64 + d];
    a.x = (a.x + q.x) * linv;
    a.y = (a.y + q.y) * linv;
    a.z = (a.z + q.z) * linv;
    a.w = (a.w + q.w) * linv;
    *(float4*)&out[o] = a;
}

extern "C" void kernel_launch(void* const* d_in, const int* in_sizes, int n_in,
                              void* d_out, int out_size, void* d_ws, size_t ws_size,
                              hipStream_t stream) {
    const float* x     = (const float*)d_in[0];
    const float* y     = (const float*)d_in[1];
    const float* k_w   = (const float*)d_in[2];
    const float* k_b   = (const float*)d_in[3];
    const float* qv_w  = (const float*)d_in[4];
    const float* qv_b  = (const float*)d_in[5];
    const float* lnx_g = (const float*)d_in[6];
    const float* lnx_b = (const float*)d_in[7];
    const float* lny_g = (const float*)d_in[8];
    const float* lny_b = (const float*)d_in[9];
    float* out = (float*)d_out;

    char* ws = (char*)d_ws;
    float* bias = (float*)ws;                 // 1536 f32 (6144 B, 16B-aligned)
    short* T    = (short*)(ws + 6144);        // 9,437,184 B
    short* Wt   = T + 4718592;                // 1,572,864 B
    short* QVK  = Wt + 786432;                // 28,311,552 B (V region unused)
    short* VT   = QVK + 14155776;             // 9,437,184 B  -> ends at 48,764,928
    float* O1   = (float*)(ws + 48764928);    // 18,874,368 B (half-1 partial O)
    float* l0   = (float*)(ws + 67639296);    // 294,912 B
    float* l1   = (float*)(ws + 67934208);    // 294,912 B -> ends at 68,229,120

    k_pre  <<<1344, 256, 0, stream>>>(x, y, qv_w, k_w, qv_b, k_b,
                                      lnx_g, lnx_b, lny_g, lny_b, T, Wt, bias);
    k_gemm <<<dim3(18, 12, 4), 256, 0, stream>>>(T, Wt, bias, QVK, VT);
    k_attn <<<2304, 256, 0, stream>>>(QVK, VT, out, O1, l0, l1);
    k_norm <<<4608, 256, 0, stream>>>(out, O1, l0, l1);
}

// Round 6
// 200.250 us; speedup vs baseline: 1.1266x; 1.0101x over previous
//
#include <hip/hip_runtime.h>

#define DIM 512
#define NTOK 2304
#define HEADS 8
#define HD 64
#define LN_EPS 1e-5f
#define BNC 2359296   // B*N*C = 2*2304*512
#define QSC 0.18033688011112042f   // 0.125 * log2(e): softmax in exp2 domain

typedef __attribute__((ext_vector_type(8))) short short8;
typedef __attribute__((ext_vector_type(4))) short sh4;
typedef __attribute__((ext_vector_type(4))) float f32x4;

__device__ __forceinline__ short f2bf(float f) {
    union { float f; unsigned u; } x; x.f = f;
    unsigned r = (x.u + 0x7fffu + ((x.u >> 16) & 1u)) >> 16;
    return (short)(r & 0xffffu);
}
__device__ __forceinline__ unsigned fbits(float f) {
    union { float f; unsigned u; } x; x.f = f; return x.u;
}
// async global->LDS DMA, 16B/lane; lds dest = wave-uniform base + lane*16
__device__ __forceinline__ void gl2lds(const short* g, short* l) {
    __builtin_amdgcn_global_load_lds(
        (const __attribute__((address_space(1))) unsigned int*)g,
        (__attribute__((address_space(3))) unsigned int*)l, 16, 0, 0);
}

// -------- fused pre: stats+normalize+transpose (blocks 0..1151) + weight transpose (1152..1343) --------
__global__ void k_pre(const float* __restrict__ x, const float* __restrict__ y,
                      const float* __restrict__ qv_w, const float* __restrict__ k_w,
                      const float* __restrict__ qv_b, const float* __restrict__ k_b,
                      const float* __restrict__ gx, const float* __restrict__ bx,
                      const float* __restrict__ gy, const float* __restrict__ by,
                      short* __restrict__ T, short* __restrict__ Wt,
                      float* __restrict__ bias) {
    __shared__ __align__(16) float tile[64][65];
    __shared__ float pS[4][64], pQ[4][64];
    __shared__ float muL[64], rsL[64];
    int bkid = blockIdx.x, tid = threadIdx.x;
    if (bkid < 1152) {
        int nt = bkid % 36, ct = (bkid / 36) % 8, sb = bkid / 288;
        int s = sb >> 1, b = sb & 1;
        int n0 = nt * 64, c0 = ct * 64;
        const float* src = (s ? y : x) + (size_t)b * DIM * NTOK;
        // phase 1: LN stats for tokens n0..n0+63 (full 512-c read, 4-way split)
        int nl = tid & 63, part = tid >> 6;
        {
            const float* p = src + n0 + nl;
            float sum = 0.f, sq = 0.f;
            for (int c = part * 128; c < part * 128 + 128; c++) {
                float v = p[(size_t)c * NTOK];
                sum += v; sq += v * v;
            }
            pS[part][nl] = sum; pQ[part][nl] = sq;
        }
        __syncthreads();
        if (tid < 64) {
            float ts = pS[0][tid] + pS[1][tid] + pS[2][tid] + pS[3][tid];
            float tq = pQ[0][tid] + pQ[1][tid] + pQ[2][tid] + pQ[3][tid];
            float m = ts * (1.0f / DIM);
            float var = tq * (1.0f / DIM) - m * m;
            muL[tid] = m;
            rsL[tid] = rsqrtf(var + LN_EPS);
        }
        // phase 2: load c-tile, normalize, transpose-store
        for (int slot = tid; slot < 1024; slot += 256) {
            int r = slot >> 4, q = slot & 15;
            const float* p = src + (size_t)(c0 + r) * NTOK + n0 + q * 4;
            float4 v = *(const float4*)p;
            tile[r][q*4+0] = v.x; tile[r][q*4+1] = v.y;
            tile[r][q*4+2] = v.z; tile[r][q*4+3] = v.w;
        }
        __syncthreads();   // covers muL/rsL and tile
        const float* g  = s ? gy : gx;
        const float* be = s ? by : bx;
        int nr = tid >> 2, cg = tid & 3;
        float m = muL[nr], r_ = rsL[nr];
        short8 o0, o1;
        for (int i = 0; i < 8; i++) {
            int c = c0 + cg * 16 + i;
            o0[i] = f2bf((tile[cg*16+i][nr] - m) * r_ * g[c] + be[c]);
        }
        for (int i = 0; i < 8; i++) {
            int c = c0 + cg * 16 + 8 + i;
            o1[i] = f2bf((tile[cg*16+8+i][nr] - m) * r_ * g[c] + be[c]);
        }
        short* dst = T + ((size_t)sb * NTOK + n0 + nr) * DIM + c0 + cg * 16;
        *(short8*)dst = o0;
        *(short8*)(dst + 8) = o1;
        return;
    }
    // ---- weight transpose blocks ----
    int idx = bkid - 1152;
    int jt = idx % 24, ct = idx / 24;
    int j0 = jt * 64, c0 = ct * 64;
    if (ct == 0 && tid < 64) {
        int j = j0 + tid;
        bias[j] = (j < 1024) ? qv_b[j] : k_b[j - 1024];
    }
    for (int slot = tid; slot < 1024; slot += 256) {
        int r = slot >> 4, q = slot & 15;
        int c = c0 + r;
        float4 v;
        if (j0 < 1024) v = *(const float4*)(qv_w + (size_t)c * 1024 + j0 + q * 4);
        else           v = *(const float4*)(k_w  + (size_t)c * 512  + (j0 - 1024) + q * 4);
        tile[r][q*4+0] = v.x; tile[r][q*4+1] = v.y;
        tile[r][q*4+2] = v.z; tile[r][q*4+3] = v.w;
    }
    __syncthreads();
    int jr = tid >> 2, cg = tid & 3;
    short8 o0, o1;
    for (int i = 0; i < 8; i++) o0[i] = f2bf(tile[cg*16+i][jr]);
    for (int i = 0; i < 8; i++) o1[i] = f2bf(tile[cg*16+8+i][jr]);
    short* dst = Wt + (size_t)(j0 + jr) * DIM + c0 + cg * 16;
    *(short8*)dst = o0;
    *(short8*)(dst + 8) = o1;
}

// -------- GEMM: 128x128 tile, DMA staging + XOR swizzle, Q pre-scaled --------
__global__ void __launch_bounds__(256)
k_gemm(const short* __restrict__ T, const short* __restrict__ Wt,
       const float* __restrict__ bias, short* __restrict__ QVK,
       short* __restrict__ VT) {
    __shared__ __align__(16) short smem[2 * 128 * 64];
    short* As = smem;
    short* Bs = smem + 128 * 64;
    int n0 = blockIdx.x * 128, j0 = blockIdx.y * 128, sb = blockIdx.z;
    int tid = threadIdx.x;
    int w = tid >> 6, l = tid & 63;
    int wr = w >> 1, wc = w & 1;
    int lrow = l & 15, quad = l >> 4;
    int r_in = (l >> 3) & 7, cc = l & 7;
    int ch = cc ^ r_in;                       // swizzled source chunk
    int sw0 = (quad ^ (lrow & 7)) * 8;        // frag-read chunk offset (shorts)
    const short* Ab = T + (size_t)sb * NTOK * DIM;
    f32x4 acc[4][4] = {};
    for (int kk = 0; kk < 8; kk++) {
        if (kk) __syncthreads();
        for (int inst = 0; inst < 4; inst++) {
            int R = w * 32 + inst * 8 + r_in;
            gl2lds(Ab + (size_t)(n0 + R) * 512 + kk * 64 + ch * 8,
                   &As[(w * 32 + inst * 8) * 64]);
            gl2lds(Wt + (size_t)(j0 + R) * 512 + kk * 64 + ch * 8,
                   &Bs[(w * 32 + inst * 8) * 64]);
        }
        __syncthreads();
        for (int c2 = 0; c2 < 2; c2++) {
            int off = c2 ? (sw0 ^ 32) : sw0;
            short8 af[4], bf[4];
            for (int i = 0; i < 4; i++)
                af[i] = *(const short8*)&As[(wr*64 + i*16 + lrow) * 64 + off];
            for (int j = 0; j < 4; j++)
                bf[j] = *(const short8*)&Bs[(wc*64 + j*16 + lrow) * 64 + off];
            for (int i = 0; i < 4; i++)
                for (int j = 0; j < 4; j++)
                    acc[i][j] = __builtin_amdgcn_mfma_f32_16x16x32_bf16(af[i], bf[j], acc[i][j], 0, 0, 0);
        }
    }
    if (j0 >= 512 && j0 < 1024) {
        // ---- V block: transpose tile in LDS (reuse As+Bs as 128x128), write VT ----
        __syncthreads();               // main-loop LDS readers done
        for (int i = 0; i < 4; i++)
            for (int j = 0; j < 4; j++) {
                int jloc = wc * 64 + j * 16 + lrow;           // V row (within tile)
                float bv = bias[j0 + jloc];
                int nloc = wr * 64 + i * 16 + quad * 4;       // n col
                int c8 = nloc >> 3, half = (nloc >> 2) & 1;
                sh4 pk;
                for (int reg = 0; reg < 4; reg++) pk[reg] = f2bf(acc[i][j][reg] + bv);
                *(sh4*)&smem[jloc * 128 + ((c8 ^ (jloc & 15)) * 8) + half * 4] = pk;
            }
        __syncthreads();
        for (int slot = tid; slot < 2048; slot += 256) {
            int row = slot >> 4, seg = slot & 15;
            short8 v = *(const short8*)&smem[row * 128 + ((seg ^ (row & 15)) * 8)];
            *(short8*)(VT + ((size_t)sb * 512 + (j0 - 512) + row) * NTOK + n0 + seg * 8) = v;
        }
    } else {
        for (int i = 0; i < 4; i++)
            for (int j = 0; j < 4; j++) {
                int jj = j0 + wc * 64 + j * 16 + lrow;
                float bv = bias[jj];
                float sc = (jj < 512) ? QSC : 1.0f;   // Q pre-scaled into exp2 domain
                for (int reg = 0; reg < 4; reg++) {
                    int n = n0 + wr * 64 + i * 16 + quad * 4 + reg;
                    QVK[((size_t)sb * NTOK + n) * 1536 + jj] = f2bf((acc[i][j][reg] + bv) * sc);
                }
            }
    }
}

// ---------------- flash attention: KV-split x2 + double-buffered K/V (1 barrier/tile) ----------------
// R16 (kept): KV loop split exactly across 2 blocks (plain sum-exp2 softmax,
// no running max). Grid 2304 = 9.0 blocks/CU even.
// R17: per-CU accounting at R5 counters: VALU 60% + MFMA 24% ~= 84% of cycles;
// remaining serialization = 2 barriers/tile (each __syncthreads drains
// vmcnt+lgkmcnt, 4 waves lockstep). Double-buffer K/V (LDS 24->40 KB, still
// >=4 blocks/CU vs ~2.8 measured resident): ds_write of tile t+1 overlaps
// compute of tile t in the other buffer -> 1 barrier/tile (19 vs 37).
// Also exp2f -> __builtin_amdgcn_exp2f (guaranteed single v_exp_f32; exp is
// the dominant VALU term at 16 quarter-rate exps per wave-tile).
__global__ void __launch_bounds__(256)
k_attn(const short* __restrict__ QVK, const short* __restrict__ VT,
       float* __restrict__ out, float* __restrict__ O1,
       float* __restrict__ l0, float* __restrict__ l1) {
    __shared__ __align__(16) short Kbuf[2][64 * 64];
    __shared__ __align__(16) short Vbuf[2][64 * 64];
    __shared__ __align__(16) short Qs[64 * 64];   // Q staging; re-used as P (wave-private)
    int id = blockIdx.x;              // 0..2303
    int half = id / 1152;             // KV half
    int rid = id % 1152;
    int xcd = rid & 7, rem = rid >> 3;
    int qt = rem % 36, yhi = rem / 36;
    int yb = yhi * 8 + xcd;           // 0..31
    int br = yb >> 4;
    int b  = (yb >> 3) & 1;
    int h  = yb & 7;
    int tid = threadIdx.x;
    int w = tid >> 6, l = tid & 63;
    int lrow = l & 15, quad = l >> 4;
    int r_in = (l >> 3) & 7, cc = l & 7;
    int ch = cc ^ r_in;
    int sw0 = (quad ^ (lrow & 7)) * 8;
    int n0 = qt * 64;
    int m_base = half * 1152;         // 18 tiles x 64 rows
    const short* Qg = QVK + ((size_t)(br * 2 + b) * NTOK) * 1536 + h * 64;           // exp2-scaled Q
    const short* Kg = QVK + ((size_t)((1 - br) * 2 + b) * NTOK) * 1536 + 1024 + h * 64;
    const short* Vg = VT + ((size_t)(br * 2 + b) * 512 + h * 64) * NTOK;

    // stage Q (wave w: rows w*16..w*16+15)
    for (int inst = 0; inst < 2; inst++) {
        int R = w * 16 + inst * 8 + r_in;
        gl2lds(Qg + (size_t)(n0 + R) * 1536 + ch * 8, &Qs[(w * 16 + inst * 8) * 64]);
    }

    // per-thread global source addresses (row pair of this wave's 16-row slab)
    const short* KnA = Kg + (size_t)(m_base + w * 16 + r_in) * 1536 + ch * 8;
    const short* KnB = Kg + (size_t)(m_base + w * 16 + 8 + r_in) * 1536 + ch * 8;
    const short* VnA = Vg + (size_t)(w * 16 + r_in) * NTOK + m_base + ch * 8;
    const short* VnB = Vg + (size_t)(w * 16 + 8 + r_in) * NTOK + m_base + ch * 8;
    int lds_off = l * 8;              // lane slot (8-row linear groups)

    // prefetch tile 0 into regs (flies under the Q drain + bq reads)
    short8 ka = *(const short8*)(KnA);
    short8 kb = *(const short8*)(KnB);
    short8 va = *(const short8*)(VnA);
    short8 vb = *(const short8*)(VnB);
    KnA += (size_t)64 * 1536; KnB += (size_t)64 * 1536;
    VnA += 64; VnB += 64;

    __syncthreads();                  // Q staged (drains gl2lds + tile0 loads)
    short8 bq0 = *(const short8*)&Qs[(w * 16 + lrow) * 64 + sw0];
    short8 bq1 = *(const short8*)&Qs[(w * 16 + lrow) * 64 + (sw0 ^ 32)];
    short* Pw = &Qs[w * 16 * 64];     // wave-private P region (16 rows)

    // write tile 0 into buf0, then issue tile-1 loads
    *(short8*)&Kbuf[0][(w * 16)     * 64 + lds_off] = ka;
    *(short8*)&Kbuf[0][(w * 16 + 8) * 64 + lds_off] = kb;
    *(short8*)&Vbuf[0][(w * 16)     * 64 + lds_off] = va;
    *(short8*)&Vbuf[0][(w * 16 + 8) * 64 + lds_off] = vb;
    ka = *(const short8*)(KnA);
    kb = *(const short8*)(KnB);
    va = *(const short8*)(VnA);
    vb = *(const short8*)(VnB);
    KnA += (size_t)64 * 1536; KnB += (size_t)64 * 1536;
    VnA += 64; VnB += 64;

    short8 ones;
    for (int i = 0; i < 8; i++) ones[i] = (short)0x3F80;   // bf16 1.0

    f32x4 Oacc[4] = {};
    f32x4 lacc = {};
    int cur = 0;

    for (int mt = 0; mt < 18; mt++) {
        __syncthreads();              // buf[cur]=tile mt visible; readers of buf[cur^1] done
        const short* Ks = Kbuf[cur];
        const short* Vs = Vbuf[cur];

        for (int sub = 0; sub < 4; sub++) {
            short8 ak0 = *(const short8*)&Ks[(sub * 16 + lrow) * 64 + sw0];
            short8 ak1 = *(const short8*)&Ks[(sub * 16 + lrow) * 64 + (sw0 ^ 32)];
            f32x4 a = {};
            a = __builtin_amdgcn_mfma_f32_16x16x32_bf16(ak0, bq0, a, 0, 0, 0);
            a = __builtin_amdgcn_mfma_f32_16x16x32_bf16(ak1, bq1, a, 0, 0, 0);
            float p0 = __builtin_amdgcn_exp2f(a[0]), p1 = __builtin_amdgcn_exp2f(a[1]);
            float p2 = __builtin_amdgcn_exp2f(a[2]), p3 = __builtin_amdgcn_exp2f(a[3]);
            uint2 pk;
            pk.x = __builtin_amdgcn_perm(fbits(p1), fbits(p0), 0x07060302u);
            pk.y = __builtin_amdgcn_perm(fbits(p3), fbits(p2), 0x07060302u);
            *(uint2*)&Pw[lrow * 64 + (((2 * sub + (quad >> 1)) ^ (lrow & 7)) * 8) + (quad & 1) * 4] = pk;
        }

        // PV + l-sum: same-wave LDS dep only, no barrier
        short8 ap0 = *(const short8*)&Pw[lrow * 64 + sw0];
        short8 ap1 = *(const short8*)&Pw[lrow * 64 + (sw0 ^ 32)];
        lacc = __builtin_amdgcn_mfma_f32_16x16x32_bf16(ones, ap0, lacc, 0, 0, 0);
        lacc = __builtin_amdgcn_mfma_f32_16x16x32_bf16(ones, ap1, lacc, 0, 0, 0);
        for (int ddt = 0; ddt < 4; ddt++) {
            short8 av0 = *(const short8*)&Vs[(ddt * 16 + lrow) * 64 + sw0];
            short8 av1 = *(const short8*)&Vs[(ddt * 16 + lrow) * 64 + (sw0 ^ 32)];
            Oacc[ddt] = __builtin_amdgcn_mfma_f32_16x16x32_bf16(av0, ap0, Oacc[ddt], 0, 0, 0);
            Oacc[ddt] = __builtin_amdgcn_mfma_f32_16x16x32_bf16(av1, ap1, Oacc[ddt], 0, 0, 0);
        }

        // stage tile mt+1 into the other buffer (overlaps this tile's compute;
        // regs were loaded last iteration -> vmcnt wait ~0)
        if (mt + 1 < 18) {
            *(short8*)&Kbuf[cur ^ 1][(w * 16)     * 64 + lds_off] = ka;
            *(short8*)&Kbuf[cur ^ 1][(w * 16 + 8) * 64 + lds_off] = kb;
            *(short8*)&Vbuf[cur ^ 1][(w * 16)     * 64 + lds_off] = va;
            *(short8*)&Vbuf[cur ^ 1][(w * 16 + 8) * 64 + lds_off] = vb;
        }
        // issue tile mt+2 loads (land under next tile's compute)
        if (mt + 2 < 18) {
            ka = *(const short8*)(KnA);
            kb = *(const short8*)(KnB);
            va = *(const short8*)(VnA);
            vb = *(const short8*)(VnB);
        }
        KnA += (size_t)64 * 1536; KnB += (size_t)64 * 1536;
        VnA += 64; VnB += 64;
        cur ^= 1;
    }

    // epilogue: unnormalized partial O + partial l (combined by k_norm)
    int n = n0 + w * 16 + lrow;
    if (quad == 0) (half ? l1 : l0)[yb * NTOK + n] = lacc[0];
    for (int ddt = 0; ddt < 4; ddt++) {
        float4 o;
        o.x = Oacc[ddt][0];
        o.y = Oacc[ddt][1];
        o.z = Oacc[ddt][2];
        o.w = Oacc[ddt][3];
        if (half == 0) {
            if (br == 0)
                *(float4*)&out[((size_t)b * NTOK + n) * 512 + h * 64 + ddt * 16 + quad * 4] = o;
            else
                *(float4*)&out[(size_t)BNC + ((size_t)(h * 2 + b) * NTOK + n) * 64 + ddt * 16 + quad * 4] = o;
        } else {
            *(float4*)&O1[((size_t)yb * NTOK + n) * 64 + ddt * 16 + quad * 4] = o;
        }
    }
}

// ---------------- combine + normalize: out = (out + O1) / (l0 + l1) ----------------
__global__ void __launch_bounds__(256)
k_norm(float* __restrict__ out, const float* __restrict__ O1,
       const float* __restrict__ l0, const float* __restrict__ l1) {
    int i = blockIdx.x * 256 + threadIdx.x;   // float4 index, 1,179,648 total
    int o = i * 4;
    int yb, n, d;
    if (o < BNC) {
        int b = o / (NTOK * 512);
        int r = o % (NTOK * 512);
        n = r >> 9;
        int c = r & 511;
        d = c & 63;
        yb = b * 8 + (c >> 6);
    } else {
        int o2 = o - BNC;
        int hb = o2 / (NTOK * 64);
        n = (o2 >> 6) % NTOK;
        d = o2 & 63;
        yb = 16 + (hb & 1) * 8 + (hb >> 1);
    }
    int li = yb * NTOK + n;
    float linv = 1.f / (l0[li] + l1[li]);
    float4 a = *(const float4*)&out[o];
    float4 q = *(const float4*)&O1[(size_t)li * 64 + d];
    a.x = (a.x + q.x) * linv;
    a.y = (a.y + q.y) * linv;
    a.z = (a.z + q.z) * linv;
    a.w = (a.w + q.w) * linv;
    *(float4*)&out[o] = a;
}

extern "C" void kernel_launch(void* const* d_in, const int* in_sizes, int n_in,
                              void* d_out, int out_size, void* d_ws, size_t ws_size,
                              hipStream_t stream) {
    const float* x     = (const float*)d_in[0];
    const float* y     = (const float*)d_in[1];
    const float* k_w   = (const float*)d_in[2];
    const float* k_b   = (const float*)d_in[3];
    const float* qv_w  = (const float*)d_in[4];
    const float* qv_b  = (const float*)d_in[5];
    const float* lnx_g = (const float*)d_in[6];
    const float* lnx_b = (const float*)d_in[7];
    const float* lny_g = (const float*)d_in[8];
    const float* lny_b = (const float*)d_in[9];
    float* out = (float*)d_out;

    char* ws = (char*)d_ws;
    float* bias = (float*)ws;                 // 1536 f32 (6144 B, 16B-aligned)
    short* T    = (short*)(ws + 6144);        // 9,437,184 B
    short* Wt   = T + 4718592;                // 1,572,864 B
    short* QVK  = Wt + 786432;                // 28,311,552 B (V region unused)
    short* VT   = QVK + 14155776;             // 9,437,184 B  -> ends at 48,764,928
    float* O1   = (float*)(ws + 48764928);    // 18,874,368 B (half-1 partial O)
    float* l0   = (float*)(ws + 67639296);    // 294,912 B
    float* l1   = (float*)(ws + 67934208);    // 294,912 B -> ends at 68,229,120

    k_pre  <<<1344, 256, 0, stream>>>(x, y, qv_w, k_w, qv_b, k_b,
                                      lnx_g, lnx_b, lny_g, lny_b, T, Wt, bias);
    k_gemm <<<dim3(18, 12, 4), 256, 0, stream>>>(T, Wt, bias, QVK, VT);
    k_attn <<<2304, 256, 0, stream>>>(QVK, VT, out, O1, l0, l1);
    k_norm <<<4608, 256, 0, stream>>>(out, O1, l0, l1);
}